// Round 10
// baseline (1027.750 us; speedup 1.0000x reference)
//
#include <hip/hip_runtime.h>
#include <hip/hip_fp16.h>

#define N_NODES 100000
#define N_EDGES 1600000
#define N_GRAPHS 128
#define SB 391               // src buckets (node>>8)
#define DB 1563              // dst buckets (node>>6)
#define NBLK 512             // blocks for streaming passes
#define NE4 (N_EDGES / 4)    // 400000 int4
#define CH4 782              // int4 per block (512*782 >= 400000)
#define CH64 3125            // u64 per block (exact)
#define LDX 136              // LDS stride (halves) for MFMA staging

typedef unsigned long long u64;
typedef unsigned int u32;
typedef unsigned char u8;
typedef _Float16 f16;
typedef f16 half8 __attribute__((ext_vector_type(8)));
typedef f16 half4v __attribute__((ext_vector_type(4)));
typedef float floatx4 __attribute__((ext_vector_type(4)));

// ---------------- P1: per-(srcbucket, block) counts; zero flags ----------------
__global__ __launch_bounds__(256) void k_cnt_s(const int4* __restrict__ src4,
                                               int* __restrict__ cs, int* __restrict__ flags) {
  __shared__ int h[SB];
  const int t = threadIdx.x, b = blockIdx.x;
  if (b == 0 && t < 16) flags[t] = 0;
  for (int j = t; j < SB; j += 256) h[j] = 0;
  __syncthreads();
  const int start = b * CH4, end = min(start + CH4, NE4);
  for (int i = start + t; i < end; i += 256) {
    int4 s = src4[i];
    atomicAdd(&h[s.x >> 8], 1); atomicAdd(&h[s.y >> 8], 1);
    atomicAdd(&h[s.z >> 8], 1); atomicAdd(&h[s.w >> 8], 1);
  }
  __syncthreads();
  for (int j = t; j < SB; j += 256) cs[j * NBLK + b] = h[j];
}

// ---------------- P2: scan cs over blocks; last block scans buckets -> boff_s ----------
__global__ __launch_bounds__(512) void k_scan_s(int* __restrict__ cs, int* __restrict__ ts,
                                                int* __restrict__ boff_s, int* __restrict__ flags) {
  __shared__ int s[512];
  __shared__ int lastflag;
  const int b = blockIdx.x, t = threadIdx.x;
  int v = cs[b * NBLK + t];
  s[t] = v;
  __syncthreads();
  for (int o = 1; o < 512; o <<= 1) {
    int a = (t >= o) ? s[t - o] : 0;
    __syncthreads(); s[t] += a; __syncthreads();
  }
  cs[b * NBLK + t] = s[t] - v;
  if (t == 511) atomicExch(&ts[b], s[t]);
  if (t == 0) { __threadfence(); lastflag = (atomicAdd(&flags[0], 1) == SB - 1); }
  __syncthreads();
  if (!lastflag) return;
  int v2 = (t < SB) ? atomicAdd(&ts[t], 0) : 0;
  s[t] = v2;
  __syncthreads();
  for (int o = 1; o < 512; o <<= 1) {
    int a = (t >= o) ? s[t - o] : 0;
    __syncthreads(); s[t] += a; __syncthreads();
  }
  if (t <= SB) boff_s[t] = s[t] - v2;   // t==SB: total = E
}

// ---------------- P3: scatter edges into src buckets (ed_s u64 = (d,s)), ssk8 ----------
__global__ __launch_bounds__(256) void k_scatter_s(const int4* __restrict__ src4,
                                                   const int4* __restrict__ dst4,
                                                   const int* __restrict__ cs,
                                                   const int* __restrict__ boff_s,
                                                   u64* __restrict__ ed_s, u8* __restrict__ ssk8) {
  __shared__ int cur[SB];
  const int t = threadIdx.x, b = blockIdx.x;
  for (int j = t; j < SB; j += 256) cur[j] = boff_s[j] + cs[j * NBLK + b];
  __syncthreads();
  const int start = b * CH4, end = min(start + CH4, NE4);
  for (int i = start + t; i < end; i += 256) {
    int4 s4 = src4[i]; int4 d4 = dst4[i];
    {
      int s = s4.x, d = d4.x;
      int ps = atomicAdd(&cur[s >> 8], 1);
      ed_s[ps] = ((u64)(u32)d << 32) | (u32)s;
      ssk8[ps] = (u8)(s & 255);
    }
    {
      int s = s4.y, d = d4.y;
      int ps = atomicAdd(&cur[s >> 8], 1);
      ed_s[ps] = ((u64)(u32)d << 32) | (u32)s;
      ssk8[ps] = (u8)(s & 255);
    }
    {
      int s = s4.z, d = d4.z;
      int ps = atomicAdd(&cur[s >> 8], 1);
      ed_s[ps] = ((u64)(u32)d << 32) | (u32)s;
      ssk8[ps] = (u8)(s & 255);
    }
    {
      int s = s4.w, d = d4.w;
      int ps = atomicAdd(&cur[s >> 8], 1);
      ed_s[ps] = ((u64)(u32)d << 32) | (u32)s;
      ssk8[ps] = (u8)(s & 255);
    }
  }
}

// ---------------- P4: per-(dstbucket, block) counts over src-sorted edges ----------
__global__ __launch_bounds__(256) void k_cnt_d(const u64* __restrict__ ed_s,
                                               int* __restrict__ cd) {
  __shared__ int h[DB];
  const int t = threadIdx.x, b = blockIdx.x;
  for (int j = t; j < DB; j += 256) h[j] = 0;
  __syncthreads();
  const int start = b * CH64, end = start + CH64;
  for (int i = start + t; i < end; i += 256) {
    u32 d = (u32)(ed_s[i] >> 32);
    atomicAdd(&h[d >> 6], 1);
  }
  __syncthreads();
  for (int j = t; j < DB; j += 256) cd[j * NBLK + b] = h[j];
}

// ---------------- P5: scan cd over blocks; last block scans 1563 buckets -> boff_d ------
__global__ __launch_bounds__(512) void k_scan_d(int* __restrict__ cd, int* __restrict__ td,
                                                int* __restrict__ boff_d, int* __restrict__ flags) {
  __shared__ int s[512];
  __shared__ int lastflag;
  const int b = blockIdx.x, t = threadIdx.x;
  int v = cd[b * NBLK + t];
  s[t] = v;
  __syncthreads();
  for (int o = 1; o < 512; o <<= 1) {
    int a = (t >= o) ? s[t - o] : 0;
    __syncthreads(); s[t] += a; __syncthreads();
  }
  cd[b * NBLK + t] = s[t] - v;
  if (t == 511) atomicExch(&td[b], s[t]);
  if (t == 0) { __threadfence(); lastflag = (atomicAdd(&flags[1], 1) == DB - 1); }
  __syncthreads();
  if (!lastflag) return;
  const int g = t * 4;
  int v0 = (g + 0 < DB) ? atomicAdd(&td[g + 0], 0) : 0;
  int v1 = (g + 1 < DB) ? atomicAdd(&td[g + 1], 0) : 0;
  int v2 = (g + 2 < DB) ? atomicAdd(&td[g + 2], 0) : 0;
  int v3 = (g + 3 < DB) ? atomicAdd(&td[g + 3], 0) : 0;
  int tsum = v0 + v1 + v2 + v3;
  s[t] = tsum;
  __syncthreads();
  for (int o = 1; o < 512; o <<= 1) {
    int a = (t >= o) ? s[t - o] : 0;
    __syncthreads(); s[t] += a; __syncthreads();
  }
  int excl = s[t] - tsum;
  if (g + 0 <= DB) boff_d[g + 0] = excl;
  if (g + 1 <= DB) boff_d[g + 1] = excl + v0;
  if (g + 2 <= DB) boff_d[g + 2] = excl + v0 + v1;
  if (g + 3 <= DB) boff_d[g + 3] = excl + v0 + v1 + v2;
}

// ---------------- P6: stable scatter into dst buckets; ed_d = (dl6<<26)|s ----------
__global__ __launch_bounds__(256) void k_scatter_d(const u64* __restrict__ ed_s,
                                                   const int* __restrict__ cd,
                                                   const int* __restrict__ boff_d,
                                                   u32* __restrict__ ed_d) {
  __shared__ int cur[DB];
  const int t = threadIdx.x, b = blockIdx.x;
  for (int j = t; j < DB; j += 256) cur[j] = boff_d[j] + cd[j * NBLK + b];
  __syncthreads();
  const int start = b * CH64, end = start + CH64;
  for (int i = start + t; i < end; i += 256) {
    u64 e = ed_s[i];
    u32 d = (u32)(e >> 32), s = (u32)e;
    int pd = atomicAdd(&cur[d >> 6], 1);
    ed_d[pd] = ((d & 63u) << 26) | s;
  }
}

// ---------------- P7: norms (outdeg from ssk8, indeg from ed_d) ----------
__global__ __launch_bounds__(256) void k_norms(const u8* __restrict__ ssk8,
                                               const int* __restrict__ boff_s,
                                               const u32* __restrict__ ed_d,
                                               const int* __restrict__ boff_d,
                                               float* __restrict__ norm_out,
                                               float* __restrict__ norm_in) {
  __shared__ int h[256];
  const int b = blockIdx.x, t = threadIdx.x;
  if (b < SB) {
    h[t] = 0;
    __syncthreads();
    const int lo = boff_s[b], hi = boff_s[b + 1];
    for (int i = lo + t; i < hi; i += 256) atomicAdd(&h[ssk8[i]], 1);
    __syncthreads();
    int node = (b << 8) + t;
    if (node < N_NODES) norm_out[node] = rsqrtf(fmaxf((float)h[t], 1.0f));
  } else {
    const int bb = b - SB;
    if (t < 64) h[t] = 0;
    __syncthreads();
    const int lo = boff_d[bb], hi = boff_d[bb + 1];
    for (int i = lo + t; i < hi; i += 256) atomicAdd(&h[ed_d[i] >> 26], 1);
    __syncthreads();
    if (t < 64) {
      int node = (bb << 6) + t;
      if (node < N_NODES) norm_in[node] = rsqrtf(fmaxf((float)h[t], 1.0f));
    }
  }
}

// ---------------- P8: gemm1 (MFMA fp16): h1 = (x * norm_out) @ W1 -> fp16 ----------
__global__ __launch_bounds__(256) void k_gemm1(const float* __restrict__ x,
                                               const float* __restrict__ W1,
                                               const float* __restrict__ norm_out,
                                               __half* __restrict__ h1h) {
  __shared__ __align__(16) f16 Xs[64 * LDX];
  __shared__ __align__(16) f16 Ws[64 * LDX];
  const int t = threadIdx.x;
  const int row0 = blockIdx.x * 64;

  const float4* W4 = (const float4*)W1;     // 2048 float4 = [k][n4]
  for (int i = t; i < 2048; i += 256) {
    int k = i >> 4, n4 = (i & 15) * 4;
    float4 v = W4[i];
    Ws[(n4 + 0) * LDX + k] = (f16)v.x;
    Ws[(n4 + 1) * LDX + k] = (f16)v.y;
    Ws[(n4 + 2) * LDX + k] = (f16)v.z;
    Ws[(n4 + 3) * LDX + k] = (f16)v.w;
  }
  const float4* x4 = (const float4*)x;
  #pragma unroll
  for (int i = 0; i < 8; ++i) {
    int idx = t + 256 * i;
    int r = idx >> 5, c4 = idx & 31;
    int row = row0 + r;
    float4 v = make_float4(0.f, 0.f, 0.f, 0.f);
    if (row < N_NODES) {
      float s = norm_out[row];
      v = x4[(size_t)row * 32 + c4];
      v.x *= s; v.y *= s; v.z *= s; v.w *= s;
    }
    half4v h = { (f16)v.x, (f16)v.y, (f16)v.z, (f16)v.w };
    *(half4v*)&Xs[r * LDX + c4 * 4] = h;
  }
  __syncthreads();

  const int w = t >> 6, l = t & 63;
  const int m = l & 15, quad = l >> 4;
  floatx4 c0 = {0.f,0.f,0.f,0.f}, c1 = {0.f,0.f,0.f,0.f};
  floatx4 c2 = {0.f,0.f,0.f,0.f}, c3 = {0.f,0.f,0.f,0.f};
  const f16* xrow = &Xs[(w * 16 + m) * LDX + quad * 8];
  const f16* wrow = &Ws[m * LDX + quad * 8];
  #pragma unroll
  for (int kb = 0; kb < 4; ++kb) {
    half8 a  = *(const half8*)(xrow + kb * 32);
    half8 b0 = *(const half8*)(wrow + kb * 32);
    half8 b1 = *(const half8*)(wrow + 16 * LDX + kb * 32);
    half8 b2 = *(const half8*)(wrow + 32 * LDX + kb * 32);
    half8 b3 = *(const half8*)(wrow + 48 * LDX + kb * 32);
    c0 = __builtin_amdgcn_mfma_f32_16x16x32_f16(a, b0, c0, 0, 0, 0);
    c1 = __builtin_amdgcn_mfma_f32_16x16x32_f16(a, b1, c1, 0, 0, 0);
    c2 = __builtin_amdgcn_mfma_f32_16x16x32_f16(a, b2, c2, 0, 0, 0);
    c3 = __builtin_amdgcn_mfma_f32_16x16x32_f16(a, b3, c3, 0, 0, 0);
  }
  #pragma unroll
  for (int r = 0; r < 4; ++r) {
    int row = row0 + w * 16 + quad * 4 + r;
    if (row < N_NODES + 1) {                // includes zeros dummy row N_NODES
      __half* dst = h1h + (size_t)row * 64 + m;
      dst[0]  = __float2half(c0[r]);
      dst[16] = __float2half(c1[r]);
      dst[32] = __float2half(c2[r]);
      dst[48] = __float2half(c3[r]);
    }
  }
}

// ------ P9: bucket gather L1: LDS fp32 acc per 64-node bucket, src-sorted edges -------
// epilogue fused: relu(acc*norm_in+b1) @ W2 * norm_out -> h2 (fp16)
__global__ __launch_bounds__(256) void k_gather_l1(const int* __restrict__ boff_d,
                                                   const u32* __restrict__ ed_d,
                                                   const __half* __restrict__ h1h,
                                                   const float* __restrict__ norm_in,
                                                   const float* __restrict__ norm_out,
                                                   const float* __restrict__ b1,
                                                   const float* __restrict__ W2,
                                                   __half* __restrict__ h2h) {
  __shared__ float acc[64 * 68];   // stride 68 (pad) -> 17.4 KB
  __shared__ float W2s[64 * 16];
  __shared__ float b1s[64];
  const int t = threadIdx.x, b = blockIdx.x;
  for (int i = t; i < 64 * 68; i += 256) acc[i] = 0.f;
  for (int i = t; i < 1024; i += 256) W2s[i] = W2[i];
  if (t < 64) b1s[t] = b1[t];
  __syncthreads();

  const int lo = boff_d[b], hi = boff_d[b + 1];
  const int w = t >> 6, l = t & 63;
  const int es = l >> 3;
  const u32 q = (u32)(l & 7);
  const uint4* __restrict__ h1q = (const uint4*)h1h;

  for (int i = lo + w * 16; i < hi; i += 64) {
    int iA = i + es, iB = i + 8 + es;
    u32 evA = (iA < hi) ? ed_d[iA] : (u32)N_NODES;   // dummy: dl=0, s=N (zeros row)
    u32 evB = (iB < hi) ? ed_d[iB] : (u32)N_NODES;
    u32 sA = evA & 0x3FFFFFFu, dA = evA >> 26;
    u32 sB = evB & 0x3FFFFFFu, dB = evB >> 26;
    uint4 va = h1q[sA * 8u + q];
    uint4 vb = h1q[sB * 8u + q];
    u32 pA = dA * 68u + q * 8u;
    u32 pB = dB * 68u + q * 8u;
    float2 g;
    g = __half22float2(*(__half2*)&va.x); atomicAdd(&acc[pA + 0], g.x); atomicAdd(&acc[pA + 1], g.y);
    g = __half22float2(*(__half2*)&va.y); atomicAdd(&acc[pA + 2], g.x); atomicAdd(&acc[pA + 3], g.y);
    g = __half22float2(*(__half2*)&va.z); atomicAdd(&acc[pA + 4], g.x); atomicAdd(&acc[pA + 5], g.y);
    g = __half22float2(*(__half2*)&va.w); atomicAdd(&acc[pA + 6], g.x); atomicAdd(&acc[pA + 7], g.y);
    g = __half22float2(*(__half2*)&vb.x); atomicAdd(&acc[pB + 0], g.x); atomicAdd(&acc[pB + 1], g.y);
    g = __half22float2(*(__half2*)&vb.y); atomicAdd(&acc[pB + 2], g.x); atomicAdd(&acc[pB + 3], g.y);
    g = __half22float2(*(__half2*)&vb.z); atomicAdd(&acc[pB + 4], g.x); atomicAdd(&acc[pB + 5], g.y);
    g = __half22float2(*(__half2*)&vb.w); atomicAdd(&acc[pB + 6], g.x); atomicAdd(&acc[pB + 7], g.y);
  }
  __syncthreads();

  const int nl = t >> 2, jg = t & 3;
  const int node = (b << 6) + nl;
  if (node <= N_NODES) {
    float ni = (node < N_NODES) ? norm_in[node] : 0.f;
    float no = (node < N_NODES) ? norm_out[node] : 0.f;
    float o0 = 0.f, o1 = 0.f, o2 = 0.f, o3 = 0.f;
    #pragma unroll
    for (int k = 0; k < 64; k += 4) {
      float4 r = *(float4*)&acc[nl * 68 + k];
      float h0 = fmaxf(r.x * ni + b1s[k + 0], 0.f);
      float h1v = fmaxf(r.y * ni + b1s[k + 1], 0.f);
      float h2v = fmaxf(r.z * ni + b1s[k + 2], 0.f);
      float h3v = fmaxf(r.w * ni + b1s[k + 3], 0.f);
      int j = jg * 4;
      o0 += h0 * W2s[(k + 0) * 16 + j + 0] + h1v * W2s[(k + 1) * 16 + j + 0]
          + h2v * W2s[(k + 2) * 16 + j + 0] + h3v * W2s[(k + 3) * 16 + j + 0];
      o1 += h0 * W2s[(k + 0) * 16 + j + 1] + h1v * W2s[(k + 1) * 16 + j + 1]
          + h2v * W2s[(k + 2) * 16 + j + 1] + h3v * W2s[(k + 3) * 16 + j + 1];
      o2 += h0 * W2s[(k + 0) * 16 + j + 2] + h1v * W2s[(k + 1) * 16 + j + 2]
          + h2v * W2s[(k + 2) * 16 + j + 2] + h3v * W2s[(k + 3) * 16 + j + 2];
      o3 += h0 * W2s[(k + 0) * 16 + j + 3] + h1v * W2s[(k + 1) * 16 + j + 3]
          + h2v * W2s[(k + 2) * 16 + j + 3] + h3v * W2s[(k + 3) * 16 + j + 3];
    }
    __half2 q0 = __float22half2_rn(make_float2(no * o0, no * o1));
    __half2 q1 = __float22half2_rn(make_float2(no * o2, no * o3));
    uint2 pk = make_uint2(*(u32*)&q0, *(u32*)&q1);
    *(uint2*)(h2h + (size_t)node * 16 + jg * 4) = pk;   // node==N -> no=ni=0 -> zeros
  }
}

// ------ P10: bucket gather L2: LDS fp32 acc, 16 feats ------
__global__ __launch_bounds__(256) void k_gather_l2(const int* __restrict__ boff_d,
                                                   const u32* __restrict__ ed_d,
                                                   const __half* __restrict__ h2h,
                                                   const float* __restrict__ norm_in,
                                                   float* __restrict__ agg2) {
  __shared__ float acc[64 * 20];   // stride 20 (pad) -> 5.1 KB
  const int t = threadIdx.x, b = blockIdx.x;
  for (int i = t; i < 64 * 20; i += 256) acc[i] = 0.f;
  __syncthreads();

  const int lo = boff_d[b], hi = boff_d[b + 1];
  const int w = t >> 6, l = t & 63;
  const int es = l >> 2;
  const u32 q = (u32)(l & 3);
  const u32* __restrict__ h2u = (const u32*)h2h;

  for (int i = lo + w * 16; i < hi; i += 64) {
    int idx = i + es;
    u32 ev = (idx < hi) ? ed_d[idx] : (u32)N_NODES;
    u32 s = ev & 0x3FFFFFFu, dl = ev >> 26;
    uint2 v = *(const uint2*)(h2u + s * 8u + q * 2u);
    float2 g0 = __half22float2(*(__half2*)&v.x);
    float2 g1 = __half22float2(*(__half2*)&v.y);
    u32 p = dl * 20u + q * 4u;
    atomicAdd(&acc[p + 0], g0.x); atomicAdd(&acc[p + 1], g0.y);
    atomicAdd(&acc[p + 2], g1.x); atomicAdd(&acc[p + 3], g1.y);
  }
  __syncthreads();

  const int nl = t >> 2, qq = t & 3;
  const int node = (b << 6) + nl;
  if (node < N_NODES) {
    float ni = norm_in[node];
    float4 r = *(float4*)&acc[nl * 20 + qq * 4];
    *(float4*)(agg2 + (size_t)node * 16 + qq * 4) =
        make_float4(r.x * ni, r.y * ni, r.z * ni, r.w * ni);
  }
}

// ---------------- P11: per-graph mean pool (gid sorted, no atomics) ----------------
__global__ __launch_bounds__(256) void k_pool(const float* __restrict__ agg2,
                                              const float* __restrict__ b2,
                                              const int* __restrict__ gid,
                                              float* __restrict__ out) {
  const int g = blockIdx.x;
  __shared__ int s_lo, s_hi;
  if (threadIdx.x == 0) {
    int a = 0, b = N_NODES;
    while (a < b) { int m = (a + b) >> 1; if (gid[m] < g) a = m + 1; else b = m; }
    s_lo = a;
    b = N_NODES;
    while (a < b) { int m = (a + b) >> 1; if (gid[m] < g + 1) a = m + 1; else b = m; }
    s_hi = a;
  }
  __syncthreads();
  const int lo = s_lo, hi = s_hi, cnt = hi - lo;
  const int j = threadIdx.x & 15;
  const int r = threadIdx.x >> 4;
  float acc = 0.f;
  for (int n = lo + r; n < hi; n += 16)
    acc += agg2[(size_t)n * 16 + j];

  __shared__ float red[256];
  red[threadIdx.x] = acc;
  __syncthreads();
  #pragma unroll
  for (int s = 8; s > 0; s >>= 1) {
    if (r < s) red[threadIdx.x] += red[threadIdx.x + s * 16];
    __syncthreads();
  }
  if (r == 0)
    out[g * 16 + j] = (cnt > 0) ? (red[j] / (float)cnt + b2[j]) : 0.0f;
}

extern "C" void kernel_launch(void* const* d_in, const int* in_sizes, int n_in,
                              void* d_out, int out_size, void* d_ws, size_t ws_size,
                              hipStream_t stream) {
  const float* x   = (const float*)d_in[0];
  const float* W1  = (const float*)d_in[1];
  const float* b1  = (const float*)d_in[2];
  const float* W2  = (const float*)d_in[3];
  const float* b2  = (const float*)d_in[4];
  const int*   src = (const int*)d_in[5];
  const int*   dst = (const int*)d_in[6];
  const int*   gid = (const int*)d_in[7];
  float* out = (float*)d_out;

  int* wsi = (int*)d_ws;
  float* wsf = (float*)d_ws;

  // word-offset layout (~25.6 MB total):
  float* norm_out = wsf + 0;                 // [N]
  float* norm_in  = wsf + 100000;            // [N]
  int*   ts       = wsi + 200000;            // [392]
  int*   td       = wsi + 200400;            // [1564]
  int*   boff_s   = wsi + 202000;            // [392]
  int*   boff_d   = wsi + 202400;            // [1564]
  int*   flags    = wsi + 204000;            // [16]
  int*   cs       = wsi + 204016;            // [SB*NBLK = 200192]   dead after P3
  int*   cd       = wsi + 404208;            // [DB*NBLK = 800256]   dead after P6
  u8*    ssk8     = (u8*)(wsi + 1204464);    // [E bytes]            dead after P7
  u32*   ed_d     = (u32*)(wsi + 1604464);   // [E]                  live thru P10
  u64*   ed_s     = (u64*)(wsi + 3204464);   // [E u64]              dead after P6
  // reuse: h1h over ed_s region; h2h over cd region; agg2 over h1h region
  __half* h1h     = (__half*)(wsi + 3204464);  // [(N+1)*64 halves]  written P8, dead after P9
  __half* h2h     = (__half*)(wsi + 404208);   // [(N+1)*16 halves]  written P9
  float*  agg2    = (float*)(wsi + 3204464);   // [16N]              written P10

  const int4* src4 = (const int4*)src;
  const int4* dst4 = (const int4*)dst;

  k_cnt_s     <<<NBLK, 256, 0, stream>>>(src4, cs, flags);
  k_scan_s    <<<SB, 512, 0, stream>>>(cs, ts, boff_s, flags);
  k_scatter_s <<<NBLK, 256, 0, stream>>>(src4, dst4, cs, boff_s, ed_s, ssk8);
  k_cnt_d     <<<NBLK, 256, 0, stream>>>(ed_s, cd);
  k_scan_d    <<<DB, 512, 0, stream>>>(cd, td, boff_d, flags);
  k_scatter_d <<<NBLK, 256, 0, stream>>>(ed_s, cd, boff_d, ed_d);
  k_norms     <<<SB + DB, 256, 0, stream>>>(ssk8, boff_s, ed_d, boff_d, norm_out, norm_in);
  k_gemm1     <<<(N_NODES + 64) / 64, 256, 0, stream>>>(x, W1, norm_out, h1h);
  k_gather_l1 <<<DB, 256, 0, stream>>>(boff_d, ed_d, h1h, norm_in, norm_out, b1, W2, h2h);
  k_gather_l2 <<<DB, 256, 0, stream>>>(boff_d, ed_d, h2h, norm_in, agg2);
  k_pool      <<<N_GRAPHS, 256, 0, stream>>>(agg2, b2, gid, out);
}

// Round 11
// 282.176 us; speedup vs baseline: 3.6422x; 3.6422x over previous
//
#include <hip/hip_runtime.h>
#include <hip/hip_fp16.h>

#define N_NODES 100000
#define N_EDGES 1600000
#define N_GRAPHS 128
#define SB 391               // 256-node buckets
#define CAP 4608             // padded bucket capacity (mean 4096 + 8 sigma)
#define NBLK 512             // blocks for the fused scatter pass
#define NE4 (N_EDGES / 4)    // 400000 int4
#define CH4 782              // int4 per block (512*782 >= 400000)
#define LDX 136              // LDS stride (halves) for MFMA staging

typedef unsigned long long u64;
typedef unsigned int u32;
typedef unsigned char u8;
typedef _Float16 f16;
typedef f16 half8 __attribute__((ext_vector_type(8)));
typedef f16 half4v __attribute__((ext_vector_type(4)));
typedef float floatx4 __attribute__((ext_vector_type(4)));

// ---------------- P0: init global bucket cursors ----------------
__global__ void k_init(int* __restrict__ cur_d, int* __restrict__ cur_s) {
  int t = blockIdx.x * blockDim.x + threadIdx.x;
  if (t < SB) { cur_d[t] = t * CAP; cur_s[t] = t * CAP; }
}

// ---------------- P1: fused count + reserve + scatter into padded buckets ----------
__global__ __launch_bounds__(256) void k_fuse(const int4* __restrict__ src4,
                                              const int4* __restrict__ dst4,
                                              int* __restrict__ cur_d,
                                              int* __restrict__ cur_s,
                                              u32* __restrict__ ed,
                                              u8* __restrict__ ssk8) {
  __shared__ int hd[SB], hs[SB], ld[SB], ls[SB];
  const int t = threadIdx.x, b = blockIdx.x;
  for (int j = t; j < SB; j += 256) { hd[j] = 0; hs[j] = 0; }
  __syncthreads();
  const int start = b * CH4, end = min(start + CH4, NE4);
  // pass A: count
  for (int i = start + t; i < end; i += 256) {
    int4 d = dst4[i]; int4 s = src4[i];
    atomicAdd(&hd[d.x >> 8], 1); atomicAdd(&hd[d.y >> 8], 1);
    atomicAdd(&hd[d.z >> 8], 1); atomicAdd(&hd[d.w >> 8], 1);
    atomicAdd(&hs[s.x >> 8], 1); atomicAdd(&hs[s.y >> 8], 1);
    atomicAdd(&hs[s.z >> 8], 1); atomicAdd(&hs[s.w >> 8], 1);
  }
  __syncthreads();
  // reserve ranges (one global atomic per bucket per block)
  for (int j = t; j < SB; j += 256) {
    ld[j] = atomicAdd(&cur_d[j], hd[j]);
    ls[j] = atomicAdd(&cur_s[j], hs[j]);
  }
  __syncthreads();
  // pass B: scatter (chunk is L2-warm)
  for (int i = start + t; i < end; i += 256) {
    int4 d4 = dst4[i]; int4 s4 = src4[i];
    {
      int d = d4.x, s = s4.x;
      int pd = atomicAdd(&ld[d >> 8], 1);
      ed[pd] = ((u32)(d & 255) << 24) | (u32)s;
      int ps = atomicAdd(&ls[s >> 8], 1);
      ssk8[ps] = (u8)(s & 255);
    }
    {
      int d = d4.y, s = s4.y;
      int pd = atomicAdd(&ld[d >> 8], 1);
      ed[pd] = ((u32)(d & 255) << 24) | (u32)s;
      int ps = atomicAdd(&ls[s >> 8], 1);
      ssk8[ps] = (u8)(s & 255);
    }
    {
      int d = d4.z, s = s4.z;
      int pd = atomicAdd(&ld[d >> 8], 1);
      ed[pd] = ((u32)(d & 255) << 24) | (u32)s;
      int ps = atomicAdd(&ls[s >> 8], 1);
      ssk8[ps] = (u8)(s & 255);
    }
    {
      int d = d4.w, s = s4.w;
      int pd = atomicAdd(&ld[d >> 8], 1);
      ed[pd] = ((u32)(d & 255) << 24) | (u32)s;
      int ps = atomicAdd(&ls[s >> 8], 1);
      ssk8[ps] = (u8)(s & 255);
    }
  }
}

// ------ P2: per-bucket CSR finalize + degrees/norms (padded bucket space) ----------
__global__ __launch_bounds__(256) void k_bucket_csr(const u32* __restrict__ ed,
                                                    const u8* __restrict__ ssk8,
                                                    const int* __restrict__ cur_d,
                                                    const int* __restrict__ cur_s,
                                                    int* __restrict__ row_ptr,
                                                    int* __restrict__ deg,
                                                    float* __restrict__ norm_in,
                                                    float* __restrict__ norm_out,
                                                    int* __restrict__ edge_src) {
  __shared__ int hist[256], scanbuf[256], cursor[256], hist2[256];
  const int b = blockIdx.x, t = threadIdx.x;
  const int base = b << 8;
  const int lo = b * CAP;
  const int hiD = cur_d[b];        // lo + count_d
  const int hiS = cur_s[b];        // lo + count_s
  hist[t] = 0; hist2[t] = 0;
  __syncthreads();
  for (int i = lo + t; i < hiS; i += 256) atomicAdd(&hist2[ssk8[i]], 1);
  for (int i = lo + t; i < hiD; i += 256) atomicAdd(&hist[ed[i] >> 24], 1);
  __syncthreads();
  int node = base + t;
  if (node < N_NODES)
    norm_out[node] = rsqrtf(fmaxf((float)hist2[t], 1.0f));
  int v = hist[t];
  scanbuf[t] = v;
  __syncthreads();
  for (int off = 1; off < 256; off <<= 1) {
    int a = (t >= off) ? scanbuf[t - off] : 0;
    __syncthreads(); scanbuf[t] += a; __syncthreads();
  }
  int excl = scanbuf[t] - v;
  if (node < N_NODES) {
    row_ptr[node] = lo + excl;
    deg[node] = v;
    norm_in[node] = rsqrtf(fmaxf((float)v, 1.0f));
  }
  cursor[t] = excl;
  __syncthreads();
  for (int i = lo + t; i < hiD; i += 256) {
    u32 e = ed[i];
    int p = atomicAdd(&cursor[e >> 24], 1);
    edge_src[lo + p] = (int)(e & 0x00FFFFFFu);
  }
}

// ---------------- P3: gemm1 (MFMA fp16): h1 = (x * norm_out) @ W1 -> fp16 ----------
__global__ __launch_bounds__(256) void k_gemm1(const float* __restrict__ x,
                                               const float* __restrict__ W1,
                                               const float* __restrict__ norm_out,
                                               __half* __restrict__ h1h) {
  __shared__ __align__(16) f16 Xs[64 * LDX];
  __shared__ __align__(16) f16 Ws[64 * LDX];
  const int t = threadIdx.x;
  const int row0 = blockIdx.x * 64;

  const float4* W4 = (const float4*)W1;     // 2048 float4 = [k][n4]
  for (int i = t; i < 2048; i += 256) {
    int k = i >> 4, n4 = (i & 15) * 4;
    float4 v = W4[i];
    Ws[(n4 + 0) * LDX + k] = (f16)v.x;
    Ws[(n4 + 1) * LDX + k] = (f16)v.y;
    Ws[(n4 + 2) * LDX + k] = (f16)v.z;
    Ws[(n4 + 3) * LDX + k] = (f16)v.w;
  }
  const float4* x4 = (const float4*)x;
  #pragma unroll
  for (int i = 0; i < 8; ++i) {
    int idx = t + 256 * i;                  // 0..2047
    int r = idx >> 5, c4 = idx & 31;
    int row = row0 + r;
    float4 v = make_float4(0.f, 0.f, 0.f, 0.f);
    if (row < N_NODES) {
      float s = norm_out[row];
      v = x4[(size_t)row * 32 + c4];
      v.x *= s; v.y *= s; v.z *= s; v.w *= s;
    }
    half4v h = { (f16)v.x, (f16)v.y, (f16)v.z, (f16)v.w };
    *(half4v*)&Xs[r * LDX + c4 * 4] = h;
  }
  __syncthreads();

  const int w = t >> 6, l = t & 63;
  const int m = l & 15, quad = l >> 4;
  floatx4 c0 = {0.f,0.f,0.f,0.f}, c1 = {0.f,0.f,0.f,0.f};
  floatx4 c2 = {0.f,0.f,0.f,0.f}, c3 = {0.f,0.f,0.f,0.f};
  const f16* xrow = &Xs[(w * 16 + m) * LDX + quad * 8];
  const f16* wrow = &Ws[m * LDX + quad * 8];
  #pragma unroll
  for (int kb = 0; kb < 4; ++kb) {
    half8 a  = *(const half8*)(xrow + kb * 32);
    half8 b0 = *(const half8*)(wrow + kb * 32);
    half8 b1 = *(const half8*)(wrow + 16 * LDX + kb * 32);
    half8 b2 = *(const half8*)(wrow + 32 * LDX + kb * 32);
    half8 b3 = *(const half8*)(wrow + 48 * LDX + kb * 32);
    c0 = __builtin_amdgcn_mfma_f32_16x16x32_f16(a, b0, c0, 0, 0, 0);
    c1 = __builtin_amdgcn_mfma_f32_16x16x32_f16(a, b1, c1, 0, 0, 0);
    c2 = __builtin_amdgcn_mfma_f32_16x16x32_f16(a, b2, c2, 0, 0, 0);
    c3 = __builtin_amdgcn_mfma_f32_16x16x32_f16(a, b3, c3, 0, 0, 0);
  }
  #pragma unroll
  for (int r = 0; r < 4; ++r) {
    int row = row0 + w * 16 + quad * 4 + r;
    if (row < N_NODES + 1) {                // includes zeros dummy row N_NODES
      __half* dst = h1h + (size_t)row * 64 + m;
      dst[0]  = __float2half(c0[r]);
      dst[16] = __float2half(c1[r]);
      dst[32] = __float2half(c2[r]);
      dst[48] = __float2half(c3[r]);
    }
  }
}

// ---------------- P4: fused gather(h1) -> relu(.*norm_in + b1) -> @W2 * norm_out -> h2
// one wave per node; 32 lanes/edge (u32 = 2 fp16 feats); uniform clamped 16-edge blocks
__global__ __launch_bounds__(256) void k_gather_l1(const int* __restrict__ row_ptr,
                                                   const int* __restrict__ deg,
                                                   const int* __restrict__ edge_src,
                                                   const __half* __restrict__ h1h,
                                                   const float* __restrict__ norm_in,
                                                   const float* __restrict__ norm_out,
                                                   const float* __restrict__ b1,
                                                   const float* __restrict__ W2,
                                                   __half* __restrict__ h2h) {
  __shared__ float W2s[64 * 17];   // padded stride 17
  const int t = threadIdx.x;
  for (int i = t; i < 64 * 16; i += 256) W2s[(i >> 4) * 17 + (i & 15)] = W2[i];
  if (blockIdx.x == 0 && t < 16) h2h[(size_t)N_NODES * 16 + t] = __float2half(0.f);
  __syncthreads();

  const int w = t >> 6;
  const int l = t & 63;
  const int n = blockIdx.x * 4 + w;
  const int hf = l >> 5;           // which edge of each pair
  const u32 c = (u32)(l & 31);     // feature-pair index within row

  const u32* __restrict__ h1u = (const u32*)h1h;
  const int lo = row_ptr[n], hi = lo + deg[n];

  float2 a0 = {0.f,0.f}, a1 = {0.f,0.f}, a2 = {0.f,0.f}, a3 = {0.f,0.f};
  float2 a4 = {0.f,0.f}, a5 = {0.f,0.f}, a6 = {0.f,0.f}, a7 = {0.f,0.f};
  for (int i = lo; i < hi; i += 16) {
    int idx = i + (l & 15);
    int sv = (idx < hi) ? edge_src[idx] : (int)N_NODES;   // clamp to zeros row
    int s0 = __shfl(sv,  0 + hf, 64);
    int s1 = __shfl(sv,  2 + hf, 64);
    int s2 = __shfl(sv,  4 + hf, 64);
    int s3 = __shfl(sv,  6 + hf, 64);
    int s4 = __shfl(sv,  8 + hf, 64);
    int s5 = __shfl(sv, 10 + hf, 64);
    int s6 = __shfl(sv, 12 + hf, 64);
    int s7 = __shfl(sv, 14 + hf, 64);
    u32 v0 = h1u[(u32)s0 * 32u + c];
    u32 v1 = h1u[(u32)s1 * 32u + c];
    u32 v2 = h1u[(u32)s2 * 32u + c];
    u32 v3 = h1u[(u32)s3 * 32u + c];
    u32 v4 = h1u[(u32)s4 * 32u + c];
    u32 v5 = h1u[(u32)s5 * 32u + c];
    u32 v6 = h1u[(u32)s6 * 32u + c];
    u32 v7 = h1u[(u32)s7 * 32u + c];
    float2 f;
    f = __half22float2(*(__half2*)&v0); a0.x += f.x; a0.y += f.y;
    f = __half22float2(*(__half2*)&v1); a1.x += f.x; a1.y += f.y;
    f = __half22float2(*(__half2*)&v2); a2.x += f.x; a2.y += f.y;
    f = __half22float2(*(__half2*)&v3); a3.x += f.x; a3.y += f.y;
    f = __half22float2(*(__half2*)&v4); a4.x += f.x; a4.y += f.y;
    f = __half22float2(*(__half2*)&v5); a5.x += f.x; a5.y += f.y;
    f = __half22float2(*(__half2*)&v6); a6.x += f.x; a6.y += f.y;
    f = __half22float2(*(__half2*)&v7); a7.x += f.x; a7.y += f.y;
  }
  float accx = ((a0.x + a1.x) + (a2.x + a3.x)) + ((a4.x + a5.x) + (a6.x + a7.x));
  float accy = ((a0.y + a1.y) + (a2.y + a3.y)) + ((a4.y + a5.y) + (a6.y + a7.y));
  accx += __shfl_xor(accx, 32, 64);
  accy += __shfl_xor(accy, 32, 64);

  const float ni = norm_in[n];
  const float2 bb = ((const float2*)b1)[c];
  float h1x = fmaxf(accx * ni + bb.x, 0.0f);
  float h1y = fmaxf(accy * ni + bb.y, 0.0f);

  const int j = l & 15, p = l >> 4;
  float partial = 0.f;
  #pragma unroll
  for (int kk = 0; kk < 16; kk += 2) {
    int sl = p * 8 + (kk >> 1);
    float vx = __shfl(h1x, sl, 64);
    float vy = __shfl(h1y, sl, 64);
    partial += vx * W2s[(p * 16 + kk) * 17 + j];
    partial += vy * W2s[(p * 16 + kk + 1) * 17 + j];
  }
  partial += __shfl_xor(partial, 16, 64);
  partial += __shfl_xor(partial, 32, 64);
  if (l < 16) h2h[(size_t)n * 16 + l] = __float2half(norm_out[n] * partial);
}

// ---------------- P5: gather layer2: agg2 = norm_in * sum_edges h2[src] (16 feats) ------
__global__ __launch_bounds__(256) void k_gather_l2(const int* __restrict__ row_ptr,
                                                   const int* __restrict__ deg,
                                                   const int* __restrict__ edge_src,
                                                   const __half* __restrict__ h2h,
                                                   const float* __restrict__ norm_in,
                                                   float* __restrict__ agg2) {
  const int t = threadIdx.x;
  const int w = t >> 6;
  const int l = t & 63;
  const int n = blockIdx.x * 4 + w;
  const int f2 = l & 7;
  const int p = l >> 3;            // 8 edge slices

  const u32* __restrict__ h2u = (const u32*)h2h;
  const int lo = row_ptr[n], hi = lo + deg[n];

  float ax = 0.f, ay = 0.f, bx = 0.f, by = 0.f;
  for (int base = lo; base < hi; base += 16) {
    int i1 = base + p, i2 = base + p + 8;
    int s0 = (i1 < hi) ? edge_src[i1] : (int)N_NODES;
    int s1 = (i2 < hi) ? edge_src[i2] : (int)N_NODES;
    u32 v0 = h2u[(u32)s0 * 8u + (u32)f2];
    u32 v1 = h2u[(u32)s1 * 8u + (u32)f2];
    float2 g0 = __half22float2(*(__half2*)&v0);
    float2 g1 = __half22float2(*(__half2*)&v1);
    ax += g0.x; ay += g0.y;
    bx += g1.x; by += g1.y;
  }
  float sx = ax + bx, sy = ay + by;
  sx += __shfl_xor(sx, 8, 64);  sy += __shfl_xor(sy, 8, 64);
  sx += __shfl_xor(sx, 16, 64); sy += __shfl_xor(sy, 16, 64);
  sx += __shfl_xor(sx, 32, 64); sy += __shfl_xor(sy, 32, 64);
  if (l < 8) {
    float ni = norm_in[n];
    ((float2*)agg2)[(size_t)n * 8 + f2] = make_float2(sx * ni, sy * ni);
  }
}

// ---------------- P6: per-graph mean pool (gid sorted, no atomics) ----------------
__global__ __launch_bounds__(256) void k_pool(const float* __restrict__ agg2,
                                              const float* __restrict__ b2,
                                              const int* __restrict__ gid,
                                              float* __restrict__ out) {
  const int g = blockIdx.x;
  __shared__ int s_lo, s_hi;
  if (threadIdx.x == 0) {
    int a = 0, b = N_NODES;
    while (a < b) { int m = (a + b) >> 1; if (gid[m] < g) a = m + 1; else b = m; }
    s_lo = a;
    b = N_NODES;
    while (a < b) { int m = (a + b) >> 1; if (gid[m] < g + 1) a = m + 1; else b = m; }
    s_hi = a;
  }
  __syncthreads();
  const int lo = s_lo, hi = s_hi, cnt = hi - lo;
  const int j = threadIdx.x & 15;
  const int r = threadIdx.x >> 4;
  float acc = 0.f;
  for (int n = lo + r; n < hi; n += 16)
    acc += agg2[(size_t)n * 16 + j];

  __shared__ float red[256];
  red[threadIdx.x] = acc;
  __syncthreads();
  #pragma unroll
  for (int s = 8; s > 0; s >>= 1) {
    if (r < s) red[threadIdx.x] += red[threadIdx.x + s * 16];
    __syncthreads();
  }
  if (r == 0)
    out[g * 16 + j] = (cnt > 0) ? (red[j] / (float)cnt + b2[j]) : 0.0f;
}

extern "C" void kernel_launch(void* const* d_in, const int* in_sizes, int n_in,
                              void* d_out, int out_size, void* d_ws, size_t ws_size,
                              hipStream_t stream) {
  const float* x   = (const float*)d_in[0];
  const float* W1  = (const float*)d_in[1];
  const float* b1  = (const float*)d_in[2];
  const float* W2  = (const float*)d_in[3];
  const float* b2  = (const float*)d_in[4];
  const int*   src = (const int*)d_in[5];
  const int*   dst = (const int*)d_in[6];
  const int*   gid = (const int*)d_in[7];
  float* out = (float*)d_out;

  int* wsi = (int*)d_ws;
  float* wsf = (float*)d_ws;

  // word-offset layout (~24.8 MB):
  // persistent through the conv phase:
  float* norm_out = wsf + 0;                 // [N]
  float* norm_in  = wsf + 100000;            // [N]
  int*   row_ptr  = wsi + 200000;            // [N]
  int*   deg      = wsi + 300000;            // [N]
  int*   cur_d    = wsi + 400000;            // [SB+pad]
  int*   cur_s    = wsi + 400400;            // [SB+pad]
  int*   edge_src = wsi + 400800;            // [SB*CAP = 1801728] padded bucket space
  const size_t S  = 2202528;                 // scratch base (words)
  // sort scratch (dead after k_bucket_csr):
  u8*    ssk8     = (u8*)(wsi + S);          // [SB*CAP bytes = 450432 words]
  u32*   ed       = (u32*)(wsi + S + 450432);// [SB*CAP = 1801728]
  // reuse after CSR build: h1h over {ssk8,ed}; agg2 over dead h1h; h2h after h1h
  __half* h1h     = (__half*)(wsi + S);            // [(N+1)*64 halves = 3200032 words]
  __half* h2h     = (__half*)(wsi + S + 3200032);  // [(N+1)*16 halves = 800008 words]
  float*  agg2    = (float*)(wsi + S);             // [16N words] (h1h dead by then)

  const int4* src4 = (const int4*)src;
  const int4* dst4 = (const int4*)dst;

  k_init      <<<2, 256, 0, stream>>>(cur_d, cur_s);
  k_fuse      <<<NBLK, 256, 0, stream>>>(src4, dst4, cur_d, cur_s, ed, ssk8);
  k_bucket_csr<<<SB, 256, 0, stream>>>(ed, ssk8, cur_d, cur_s, row_ptr, deg,
                                       norm_in, norm_out, edge_src);
  k_gemm1     <<<(N_NODES + 64) / 64, 256, 0, stream>>>(x, W1, norm_out, h1h);
  k_gather_l1 <<<N_NODES / 4, 256, 0, stream>>>(row_ptr, deg, edge_src, h1h,
                                                norm_in, norm_out, b1, W2, h2h);
  k_gather_l2 <<<N_NODES / 4, 256, 0, stream>>>(row_ptr, deg, edge_src, h2h,
                                                norm_in, agg2);
  k_pool      <<<N_GRAPHS, 256, 0, stream>>>(agg2, b2, gid, out);
}